// Round 4
// baseline (382.076 us; speedup 1.0000x reference)
//
#include <hip/hip_runtime.h>
#include <hip/hip_bf16.h>
#include <math.h>

// Problem: B=1, N=1024, D=1024, H=16, C=64, TOPK=2, HD=64, G=16
// Inputs (float32): x[1024,1024], Wq[1024,1024], Wk, Wv, Wg[32,1024], Wo[1024,1024]
// Output (float32): [1024,1024]
//
// Numerics: reference selects top-2 blocks from f32 scores (discrete!), so
// Q,K must be f32-accurate. All 4 big GEMMs use bf16x2 split MFMA:
//   A*B ~= Ah*Bh + Ah*Bl + Al*Bh   (rel err ~2^-17)

typedef __attribute__((ext_vector_type(8))) short short8;   // 8 bf16 = 4 VGPRs
typedef __attribute__((ext_vector_type(4))) float f32x4;

#define NTOK 1024
#define DMODEL 1024
#define NHEAD 16
#define HDIM 64
#define CHUNK 64
#define NBLK 16

// ---------------------------------------------------------------------------
// split cast: hi = bf16(v), lo = bf16(v - hi);  4 elems/thread
// ---------------------------------------------------------------------------
__global__ __launch_bounds__(256) void cast_split_f32_bf16(
    const float* __restrict__ in, __hip_bfloat16* __restrict__ hi,
    __hip_bfloat16* __restrict__ lo, int n)
{
    int i = (blockIdx.x * 256 + threadIdx.x) * 4;
    if (i < n) {
        float4 v = *(const float4*)(in + i);
        float vv[4] = {v.x, v.y, v.z, v.w};
        __hip_bfloat16 h[4], l[4];
        #pragma unroll
        for (int j = 0; j < 4; j++) {
            h[j] = __float2bfloat16(vv[j]);
            l[j] = __float2bfloat16(vv[j] - __bfloat162float(h[j]));
        }
        *(uint2*)(hi + i) = *(uint2*)h;
        *(uint2*)(lo + i) = *(uint2*)l;
    }
}

// ---------------------------------------------------------------------------
// Split GEMM: C[M,N] = A[M,K] * B[N,K]^T with A = Ah+Al, B = Bh+Bl (bf16 pairs)
// acc += Al*Bh + Ah*Bl + Ah*Bh   (f32 accumulate; lo*lo dropped)
// 64x64 tile, 256 threads = 4 waves, each wave 32x32 via 2x2 mfma 16x16x32.
// ---------------------------------------------------------------------------
__global__ __launch_bounds__(256) void gemm_bt_split(
    const __hip_bfloat16* __restrict__ Ah, const __hip_bfloat16* __restrict__ Al,
    const __hip_bfloat16* __restrict__ Bh, const __hip_bfloat16* __restrict__ Bl,
    float* __restrict__ C, int M, int N, int K)
{
    // LDS stride 40 bf16 (=80B): 16B-aligned rows, 2-way bank alias only (free)
    __shared__ alignas(16) __hip_bfloat16 Ash[64][40];
    __shared__ alignas(16) __hip_bfloat16 Asl[64][40];
    __shared__ alignas(16) __hip_bfloat16 Bsh[64][40];
    __shared__ alignas(16) __hip_bfloat16 Bsl[64][40];

    const int tid  = threadIdx.x;
    const int wave = tid >> 6;
    const int lane = tid & 63;
    const int m0 = blockIdx.y * 64;
    const int n0 = blockIdx.x * 64;
    const int lr = tid >> 2;          // 0..63 staging row
    const int lc = (tid & 3) * 8;     // staging col (bf16 elems)
    const int wm = (wave >> 1) * 32;  // wave subtile row
    const int wn = (wave & 1) * 32;   // wave subtile col
    const int fr = lane & 15;
    const int quad = lane >> 4;

    f32x4 acc[2][2] = {};

    for (int k0 = 0; k0 < K; k0 += 32) {
        const size_t aoff = (size_t)(m0 + lr) * K + k0 + lc;
        const size_t boff = (size_t)(n0 + lr) * K + k0 + lc;
        const uint4 avh = *(const uint4*)(Ah + aoff);
        const uint4 avl = *(const uint4*)(Al + aoff);
        const uint4 bvh = *(const uint4*)(Bh + boff);
        const uint4 bvl = *(const uint4*)(Bl + boff);
        *(uint4*)(&Ash[lr][lc]) = avh;
        *(uint4*)(&Asl[lr][lc]) = avl;
        *(uint4*)(&Bsh[lr][lc]) = bvh;
        *(uint4*)(&Bsl[lr][lc]) = bvl;
        __syncthreads();

        short8 a0h = *(const short8*)(&Ash[wm + fr][quad * 8]);
        short8 a1h = *(const short8*)(&Ash[wm + 16 + fr][quad * 8]);
        short8 a0l = *(const short8*)(&Asl[wm + fr][quad * 8]);
        short8 a1l = *(const short8*)(&Asl[wm + 16 + fr][quad * 8]);
        short8 b0h = *(const short8*)(&Bsh[wn + fr][quad * 8]);
        short8 b1h = *(const short8*)(&Bsh[wn + 16 + fr][quad * 8]);
        short8 b0l = *(const short8*)(&Bsl[wn + fr][quad * 8]);
        short8 b1l = *(const short8*)(&Bsl[wn + 16 + fr][quad * 8]);

        acc[0][0] = __builtin_amdgcn_mfma_f32_16x16x32_bf16(a0l, b0h, acc[0][0], 0, 0, 0);
        acc[0][1] = __builtin_amdgcn_mfma_f32_16x16x32_bf16(a0l, b1h, acc[0][1], 0, 0, 0);
        acc[1][0] = __builtin_amdgcn_mfma_f32_16x16x32_bf16(a1l, b0h, acc[1][0], 0, 0, 0);
        acc[1][1] = __builtin_amdgcn_mfma_f32_16x16x32_bf16(a1l, b1h, acc[1][1], 0, 0, 0);
        acc[0][0] = __builtin_amdgcn_mfma_f32_16x16x32_bf16(a0h, b0l, acc[0][0], 0, 0, 0);
        acc[0][1] = __builtin_amdgcn_mfma_f32_16x16x32_bf16(a0h, b1l, acc[0][1], 0, 0, 0);
        acc[1][0] = __builtin_amdgcn_mfma_f32_16x16x32_bf16(a1h, b0l, acc[1][0], 0, 0, 0);
        acc[1][1] = __builtin_amdgcn_mfma_f32_16x16x32_bf16(a1h, b1l, acc[1][1], 0, 0, 0);
        acc[0][0] = __builtin_amdgcn_mfma_f32_16x16x32_bf16(a0h, b0h, acc[0][0], 0, 0, 0);
        acc[0][1] = __builtin_amdgcn_mfma_f32_16x16x32_bf16(a0h, b1h, acc[0][1], 0, 0, 0);
        acc[1][0] = __builtin_amdgcn_mfma_f32_16x16x32_bf16(a1h, b0h, acc[1][0], 0, 0, 0);
        acc[1][1] = __builtin_amdgcn_mfma_f32_16x16x32_bf16(a1h, b1h, acc[1][1], 0, 0, 0);
        __syncthreads();
    }

    // C/D layout: col = lane&15, row = (lane>>4)*4 + reg   [verified m89/m91]
    #pragma unroll
    for (int tm = 0; tm < 2; tm++)
    #pragma unroll
    for (int tn = 0; tn < 2; tn++)
    #pragma unroll
    for (int r = 0; r < 4; r++) {
        int row = m0 + wm + tm * 16 + quad * 4 + r;
        int col = n0 + wn + tn * 16 + fr;
        C[(size_t)row * N + col] = acc[tm][tn][r];
    }
}

// ---------------------------------------------------------------------------
// Gate: softmax((x @ Wg^T).reshape(n, 16, 2), axis=-1) -> float2 per (n,h)
// exact f32; one block per token row
// ---------------------------------------------------------------------------
__global__ __launch_bounds__(256) void gate_kernel(
    const float* __restrict__ x,
    const float* __restrict__ Wg,
    float2* __restrict__ gate)
{
    __shared__ float gs[32];
    const int n = blockIdx.x;
    const int wave = threadIdx.x >> 6, lane = threadIdx.x & 63;
    #pragma unroll
    for (int jj = 0; jj < 8; jj++) {
        int j = wave * 8 + jj;
        float s = 0.f;
        #pragma unroll
        for (int t = 0; t < 16; t++) {
            int d = lane + (t << 6);
            s += x[n * DMODEL + d] * Wg[j * DMODEL + d];
        }
        #pragma unroll
        for (int off = 32; off; off >>= 1) s += __shfl_xor(s, off);
        if (lane == 0) gs[j] = s;
    }
    __syncthreads();
    if (threadIdx.x < NHEAD) {
        int h = threadIdx.x;
        float a = gs[2 * h], b = gs[2 * h + 1];
        float m = fmaxf(a, b);
        float ea = expf(a - m), eb = expf(b - m);
        float inv = 1.f / (ea + eb);
        gate[n * NHEAD + h] = make_float2(ea * inv, eb * inv);
    }
}

// ---------------------------------------------------------------------------
// k_compress[g][f] = mean over c of K[g*64+c][f]    (f = h*64+d, 1024 feats)
// ---------------------------------------------------------------------------
__global__ __launch_bounds__(256) void kcompress_kernel(
    const float* __restrict__ K, float* __restrict__ kc)
{
    const int g = blockIdx.x;
    for (int f = threadIdx.x; f < DMODEL; f += 256) {
        float s = 0.f;
        #pragma unroll 8
        for (int c = 0; c < CHUNK; c++) s += K[(size_t)(g * CHUNK + c) * DMODEL + f];
        kc[g * DMODEL + f] = s * (1.0f / CHUNK);
    }
}

// ---------------------------------------------------------------------------
// score + top-2 per (n,h). Mask: block g masked if n >= 64*g (only strictly-
// future blocks selectable, per reference). top_k tie-break: lowest index.
// For n >= 960 all scores are -inf -> idx = (0,1), matching jax.lax.top_k.
// ---------------------------------------------------------------------------
__global__ __launch_bounds__(256) void score_top2_kernel(
    const float* __restrict__ Q, const float* __restrict__ kc,
    int2* __restrict__ idx)
{
    const int t = blockIdx.x * 256 + threadIdx.x;   // t = n*16 + h
    const int n = t >> 4, h = t & 15;
    float q[HDIM];
    #pragma unroll
    for (int d = 0; d < HDIM; d++) q[d] = Q[(size_t)n * DMODEL + h * HDIM + d];
    float sc[NBLK];
    #pragma unroll
    for (int g = 0; g < NBLK; g++) {
        float s = 0.f;
        #pragma unroll
        for (int d = 0; d < HDIM; d++) s += q[d] * kc[g * DMODEL + h * HDIM + d];
        sc[g] = (n >= (g << 6)) ? -INFINITY : s;
    }
    int i1 = -1; float b1 = -INFINITY;
    #pragma unroll
    for (int g = 0; g < NBLK; g++) if (i1 < 0 || sc[g] > b1) { b1 = sc[g]; i1 = g; }
    int i2 = -1; float b2 = -INFINITY;
    #pragma unroll
    for (int g = 0; g < NBLK; g++) { if (g == i1) continue; if (i2 < 0 || sc[g] > b2) { b2 = sc[g]; i2 = g; } }
    idx[t] = make_int2(i1, i2);
}

// ---------------------------------------------------------------------------
// Intra: causal attention within each 64-chunk. One block per (g,h),
// 4 waves x 16 queries each. Q/K/V chunk staged in LDS (+1 pad).
// ---------------------------------------------------------------------------
__global__ __launch_bounds__(256) void intra_kernel(
    const float* __restrict__ Q, const float* __restrict__ K,
    const float* __restrict__ V, float* __restrict__ o_intra)
{
    __shared__ float Qs[64][65], Ks[64][65], Vs[64][65];
    const int g = blockIdx.x >> 4, h = blockIdx.x & 15;
    for (int i = threadIdx.x; i < 64 * 64; i += 256) {
        int r = i >> 6, c = i & 63;
        size_t off = (size_t)(g * CHUNK + r) * DMODEL + h * HDIM + c;
        Qs[r][c] = Q[off]; Ks[r][c] = K[off]; Vs[r][c] = V[off];
    }
    __syncthreads();
    const int wave = threadIdx.x >> 6, lane = threadIdx.x & 63;
    for (int qi = wave; qi < 64; qi += 4) {
        float s = 0.f;
        #pragma unroll 16
        for (int d = 0; d < HDIM; d++) s += Qs[qi][d] * Ks[lane][d];
        s *= 0.125f;                       // 1/sqrt(64)
        if (lane > qi) s = -INFINITY;      // causal
        float m = s;
        #pragma unroll
        for (int off = 32; off; off >>= 1) m = fmaxf(m, __shfl_xor(m, off));
        float p = expf(s - m);
        float sum = p;
        #pragma unroll
        for (int off = 32; off; off >>= 1) sum += __shfl_xor(sum, off);
        p /= sum;
        float o = 0.f;
        for (int k = 0; k <= qi; k++) {    // qi is wave-uniform: no divergence
            float pk = __shfl(p, k);
            o += pk * Vs[k][lane];
        }
        o_intra[(size_t)(g * CHUNK + qi) * DMODEL + h * HDIM + lane] = o;
    }
}

// ---------------------------------------------------------------------------
// Inter attention over 2 selected blocks (128 keys) + gated blend with intra.
// One wave per (n,h). Writes blended o (f32) IN-PLACE over Q[n, h*64+lane]:
// each wave reads its own Q element before writing; no cross-wave Q use here.
// ---------------------------------------------------------------------------
__global__ __launch_bounds__(256) void inter_blend_kernel(
    float* __restrict__ Q, const float* __restrict__ K,
    const float* __restrict__ V, const int2* __restrict__ idx,
    const float2* __restrict__ gate, const float* __restrict__ o_intra)
{
    const int wave = threadIdx.x >> 6, lane = threadIdx.x & 63;
    const int gw = blockIdx.x * 4 + wave;   // = n*16 + h
    const int n = gw >> 4, h = gw & 15;
    const int2 sel = idx[gw];
    const int r1 = sel.x * CHUNK, r2 = sel.y * CHUNK;

    const float qreg = Q[(size_t)n * DMODEL + h * HDIM + lane];
    const float* Kh = K + h * HDIM;
    float s0 = 0.f, s1 = 0.f;
    #pragma unroll 8
    for (int d = 0; d < HDIM; d++) {
        float qd = __shfl(qreg, d);
        s0 += qd * Kh[(size_t)(r1 + lane) * DMODEL + d];
        s1 += qd * Kh[(size_t)(r2 + lane) * DMODEL + d];
    }
    s0 *= 0.125f; s1 *= 0.125f;
    float m = fmaxf(s0, s1);
    #pragma unroll
    for (int off = 32; off; off >>= 1) m = fmaxf(m, __shfl_xor(m, off));
    float e0 = expf(s0 - m), e1 = expf(s1 - m);
    float sum = e0 + e1;
    #pragma unroll
    for (int off = 32; off; off >>= 1) sum += __shfl_xor(sum, off);
    float inv = 1.f / sum;
    float p0 = e0 * inv, p1 = e1 * inv;

    const float* Vh = V + h * HDIM;
    float o = 0.f;
    #pragma unroll 8
    for (int k = 0; k < CHUNK; k++) {
        float pa = __shfl(p0, k), pb = __shfl(p1, k);
        o += pa * Vh[(size_t)(r1 + k) * DMODEL + lane];
        o += pb * Vh[(size_t)(r2 + k) * DMODEL + lane];
    }
    const float2 gt = gate[gw];
    const float oi = o_intra[(size_t)n * DMODEL + h * HDIM + lane];
    Q[(size_t)n * DMODEL + h * HDIM + lane] = gt.x * o + gt.y * oi;
}

// ---------------------------------------------------------------------------
extern "C" void kernel_launch(void* const* d_in, const int* in_sizes, int n_in,
                              void* d_out, int out_size, void* d_ws, size_t ws_size,
                              hipStream_t stream)
{
    const float* x  = (const float*)d_in[0];
    const float* Wq = (const float*)d_in[1];
    const float* Wk = (const float*)d_in[2];
    const float* Wv = (const float*)d_in[3];
    const float* Wg = (const float*)d_in[4];
    const float* Wo = (const float*)d_in[5];

    // workspace layout (~24.3 MB total)
    float* Q       = (float*)d_ws;                    // 4 MB
    float* K       = Q + (1 << 20);                   // 4 MB
    float* V       = K + (1 << 20);                   // 4 MB
    float* o_intra = V + (1 << 20);                   // 4 MB
    float* kc      = o_intra + (1 << 20);             // 64 KB
    float2* gate   = (float2*)(kc + NBLK * DMODEL);   // 128 KB
    int2* idx      = (int2*)(gate + NTOK * NHEAD);    // 128 KB
    __hip_bfloat16* xh = (__hip_bfloat16*)(idx + NTOK * NHEAD);   // 2 MB (reused for o)
    __hip_bfloat16* xl = xh + (1 << 20);                          // 2 MB (reused for o)
    __hip_bfloat16* Wh = xl + (1 << 20);                          // 2 MB (reused per W)
    __hip_bfloat16* Wl = Wh + (1 << 20);                          // 2 MB

    const int NELEM = NTOK * DMODEL;          // 1M
    const int CAST_BLOCKS = NELEM / (256 * 4);
    dim3 gg(16, 16);

    cast_split_f32_bf16<<<CAST_BLOCKS, 256, 0, stream>>>(x, xh, xl, NELEM);

    cast_split_f32_bf16<<<CAST_BLOCKS, 256, 0, stream>>>(Wq, Wh, Wl, NELEM);
    gemm_bt_split<<<gg, 256, 0, stream>>>(xh, xl, Wh, Wl, Q, NTOK, DMODEL, DMODEL);
    cast_split_f32_bf16<<<CAST_BLOCKS, 256, 0, stream>>>(Wk, Wh, Wl, NELEM);
    gemm_bt_split<<<gg, 256, 0, stream>>>(xh, xl, Wh, Wl, K, NTOK, DMODEL, DMODEL);
    cast_split_f32_bf16<<<CAST_BLOCKS, 256, 0, stream>>>(Wv, Wh, Wl, NELEM);
    gemm_bt_split<<<gg, 256, 0, stream>>>(xh, xl, Wh, Wl, V, NTOK, DMODEL, DMODEL);

    gate_kernel<<<NTOK, 256, 0, stream>>>(x, Wg, gate);
    kcompress_kernel<<<NBLK, 256, 0, stream>>>(K, kc);
    score_top2_kernel<<<NTOK * NHEAD / 256, 256, 0, stream>>>(Q, kc, idx);
    intra_kernel<<<NBLK * NHEAD, 256, 0, stream>>>(Q, K, V, o_intra);
    inter_blend_kernel<<<NTOK * NHEAD / 4, 256, 0, stream>>>(Q, K, V, idx, gate, o_intra);

    // Q now holds the blended o (f32). Split-cast it (reusing x buffers) and
    // run the final split GEMM straight into d_out (f32).
    cast_split_f32_bf16<<<CAST_BLOCKS, 256, 0, stream>>>(Q, xh, xl, NELEM);
    cast_split_f32_bf16<<<CAST_BLOCKS, 256, 0, stream>>>(Wo, Wh, Wl, NELEM);
    gemm_bt_split<<<gg, 256, 0, stream>>>(xh, xl, Wh, Wl, (float*)d_out, NTOK, DMODEL, DMODEL);
}

// Round 5
// 356.272 us; speedup vs baseline: 1.0724x; 1.0724x over previous
//
#include <hip/hip_runtime.h>
#include <hip/hip_bf16.h>
#include <math.h>

// Problem: B=1, N=1024, D=1024, H=16, C=64, TOPK=2, HD=64, G=16
// Inputs (float32): x[1024,1024], Wq[1024,1024], Wk, Wv, Wg[32,1024], Wo[1024,1024]
// Output (float32): [1024,1024]
//
// Numerics: bf16x2 split MFMA (Ah*Bh + Ah*Bl + Al*Bh, f32 accumulate) for all
// big GEMMs; hi/lo split happens in-register during LDS staging (no casts).
// Attention math exact f32. Inter attention = flash-style split over the 2
// selected blocks: per-(g,h) partials (m,l,o_unnorm) + combine.

typedef __attribute__((ext_vector_type(8))) short short8;   // 8 bf16 = 4 VGPRs
typedef __attribute__((ext_vector_type(4))) float f32x4;

#define NTOK 1024
#define DMODEL 1024
#define NHEAD 16
#define HDIM 64
#define CHUNK 64
#define NBLK 16

// ---------------------------------------------------------------------------
// helper: load 8 f32, split into hi/lo bf16 short8
// ---------------------------------------------------------------------------
__device__ inline void split8(const float* p, short8& hi, short8& lo)
{
    float4 v0 = *(const float4*)p;
    float4 v1 = *(const float4*)(p + 4);
    float vv[8] = {v0.x, v0.y, v0.z, v0.w, v1.x, v1.y, v1.z, v1.w};
    union { short8 s; __hip_bfloat16 b[8]; } h, l;
    #pragma unroll
    for (int j = 0; j < 8; j++) {
        h.b[j] = __float2bfloat16(vv[j]);
        l.b[j] = __float2bfloat16(vv[j] - __bfloat162float(h.b[j]));
    }
    hi = h.s; lo = l.s;
}

// ---------------------------------------------------------------------------
// shared split-GEMM K-loop body (macro'd via device function on LDS refs is
// awkward; just duplicate in the two kernels).
// LDS stride 40 bf16 (=80B): 16B-aligned rows, 2-way bank alias only (free)
// ---------------------------------------------------------------------------

// QKV fused: C[M,3072] conceptually; blockIdx.x in [0,48): widx=x>>4 selects
// Wq/Wk/Wv and output Q/K/V; col0=(x&15)*64. A = x (f32), B = W (f32).
__global__ __launch_bounds__(256) void gemm_qkv(
    const float* __restrict__ x,
    const float* __restrict__ Wq, const float* __restrict__ Wk,
    const float* __restrict__ Wv,
    float* __restrict__ Q, float* __restrict__ K, float* __restrict__ V)
{
    __shared__ alignas(16) __hip_bfloat16 Ash[64][40];
    __shared__ alignas(16) __hip_bfloat16 Asl[64][40];
    __shared__ alignas(16) __hip_bfloat16 Bsh[64][40];
    __shared__ alignas(16) __hip_bfloat16 Bsl[64][40];

    const int widx = blockIdx.x >> 4;
    const float* __restrict__ B = (widx == 0) ? Wq : (widx == 1) ? Wk : Wv;
    float* __restrict__ C = (widx == 0) ? Q : (widx == 1) ? K : V;
    const int n0 = (blockIdx.x & 15) * 64;
    const int m0 = blockIdx.y * 64;

    const int tid  = threadIdx.x;
    const int wave = tid >> 6;
    const int lane = tid & 63;
    const int lr = tid >> 2;          // staging row
    const int lc = (tid & 3) * 8;     // staging col
    const int wm = (wave >> 1) * 32;
    const int wn = (wave & 1) * 32;
    const int fr = lane & 15;
    const int quad = lane >> 4;

    f32x4 acc[2][2] = {};

    for (int k0 = 0; k0 < DMODEL; k0 += 32) {
        short8 ah, al, bh, bl;
        split8(x + (size_t)(m0 + lr) * DMODEL + k0 + lc, ah, al);
        split8(B + (size_t)(n0 + lr) * DMODEL + k0 + lc, bh, bl);
        *(short8*)(&Ash[lr][lc]) = ah;
        *(short8*)(&Asl[lr][lc]) = al;
        *(short8*)(&Bsh[lr][lc]) = bh;
        *(short8*)(&Bsl[lr][lc]) = bl;
        __syncthreads();

        short8 a0h = *(const short8*)(&Ash[wm + fr][quad * 8]);
        short8 a1h = *(const short8*)(&Ash[wm + 16 + fr][quad * 8]);
        short8 a0l = *(const short8*)(&Asl[wm + fr][quad * 8]);
        short8 a1l = *(const short8*)(&Asl[wm + 16 + fr][quad * 8]);
        short8 b0h = *(const short8*)(&Bsh[wn + fr][quad * 8]);
        short8 b1h = *(const short8*)(&Bsh[wn + 16 + fr][quad * 8]);
        short8 b0l = *(const short8*)(&Bsl[wn + fr][quad * 8]);
        short8 b1l = *(const short8*)(&Bsl[wn + 16 + fr][quad * 8]);

        acc[0][0] = __builtin_amdgcn_mfma_f32_16x16x32_bf16(a0l, b0h, acc[0][0], 0, 0, 0);
        acc[0][1] = __builtin_amdgcn_mfma_f32_16x16x32_bf16(a0l, b1h, acc[0][1], 0, 0, 0);
        acc[1][0] = __builtin_amdgcn_mfma_f32_16x16x32_bf16(a1l, b0h, acc[1][0], 0, 0, 0);
        acc[1][1] = __builtin_amdgcn_mfma_f32_16x16x32_bf16(a1l, b1h, acc[1][1], 0, 0, 0);
        acc[0][0] = __builtin_amdgcn_mfma_f32_16x16x32_bf16(a0h, b0l, acc[0][0], 0, 0, 0);
        acc[0][1] = __builtin_amdgcn_mfma_f32_16x16x32_bf16(a0h, b1l, acc[0][1], 0, 0, 0);
        acc[1][0] = __builtin_amdgcn_mfma_f32_16x16x32_bf16(a1h, b0l, acc[1][0], 0, 0, 0);
        acc[1][1] = __builtin_amdgcn_mfma_f32_16x16x32_bf16(a1h, b1l, acc[1][1], 0, 0, 0);
        acc[0][0] = __builtin_amdgcn_mfma_f32_16x16x32_bf16(a0h, b0h, acc[0][0], 0, 0, 0);
        acc[0][1] = __builtin_amdgcn_mfma_f32_16x16x32_bf16(a0h, b1h, acc[0][1], 0, 0, 0);
        acc[1][0] = __builtin_amdgcn_mfma_f32_16x16x32_bf16(a1h, b0h, acc[1][0], 0, 0, 0);
        acc[1][1] = __builtin_amdgcn_mfma_f32_16x16x32_bf16(a1h, b1h, acc[1][1], 0, 0, 0);
        __syncthreads();
    }

    #pragma unroll
    for (int tm = 0; tm < 2; tm++)
    #pragma unroll
    for (int tn = 0; tn < 2; tn++)
    #pragma unroll
    for (int r = 0; r < 4; r++) {
        int row = m0 + wm + tm * 16 + quad * 4 + r;
        int col = n0 + wn + tn * 16 + fr;
        C[(size_t)row * DMODEL + col] = acc[tm][tn][r];
    }
}

// Wo GEMM, split-K=2: blockIdx.z selects K-half; atomicAdd into zeroed C.
__global__ __launch_bounds__(256) void gemm_wo_splitk(
    const float* __restrict__ A, const float* __restrict__ B,
    float* __restrict__ C)
{
    __shared__ alignas(16) __hip_bfloat16 Ash[64][40];
    __shared__ alignas(16) __hip_bfloat16 Asl[64][40];
    __shared__ alignas(16) __hip_bfloat16 Bsh[64][40];
    __shared__ alignas(16) __hip_bfloat16 Bsl[64][40];

    const int n0 = blockIdx.x * 64;
    const int m0 = blockIdx.y * 64;
    const int kbeg = blockIdx.z * (DMODEL / 2);
    const int kend = kbeg + (DMODEL / 2);

    const int tid  = threadIdx.x;
    const int wave = tid >> 6;
    const int lane = tid & 63;
    const int lr = tid >> 2;
    const int lc = (tid & 3) * 8;
    const int wm = (wave >> 1) * 32;
    const int wn = (wave & 1) * 32;
    const int fr = lane & 15;
    const int quad = lane >> 4;

    f32x4 acc[2][2] = {};

    for (int k0 = kbeg; k0 < kend; k0 += 32) {
        short8 ah, al, bh, bl;
        split8(A + (size_t)(m0 + lr) * DMODEL + k0 + lc, ah, al);
        split8(B + (size_t)(n0 + lr) * DMODEL + k0 + lc, bh, bl);
        *(short8*)(&Ash[lr][lc]) = ah;
        *(short8*)(&Asl[lr][lc]) = al;
        *(short8*)(&Bsh[lr][lc]) = bh;
        *(short8*)(&Bsl[lr][lc]) = bl;
        __syncthreads();

        short8 a0h = *(const short8*)(&Ash[wm + fr][quad * 8]);
        short8 a1h = *(const short8*)(&Ash[wm + 16 + fr][quad * 8]);
        short8 a0l = *(const short8*)(&Asl[wm + fr][quad * 8]);
        short8 a1l = *(const short8*)(&Asl[wm + 16 + fr][quad * 8]);
        short8 b0h = *(const short8*)(&Bsh[wn + fr][quad * 8]);
        short8 b1h = *(const short8*)(&Bsh[wn + 16 + fr][quad * 8]);
        short8 b0l = *(const short8*)(&Bsl[wn + fr][quad * 8]);
        short8 b1l = *(const short8*)(&Bsl[wn + 16 + fr][quad * 8]);

        acc[0][0] = __builtin_amdgcn_mfma_f32_16x16x32_bf16(a0l, b0h, acc[0][0], 0, 0, 0);
        acc[0][1] = __builtin_amdgcn_mfma_f32_16x16x32_bf16(a0l, b1h, acc[0][1], 0, 0, 0);
        acc[1][0] = __builtin_amdgcn_mfma_f32_16x16x32_bf16(a1l, b0h, acc[1][0], 0, 0, 0);
        acc[1][1] = __builtin_amdgcn_mfma_f32_16x16x32_bf16(a1l, b1h, acc[1][1], 0, 0, 0);
        acc[0][0] = __builtin_amdgcn_mfma_f32_16x16x32_bf16(a0h, b0l, acc[0][0], 0, 0, 0);
        acc[0][1] = __builtin_amdgcn_mfma_f32_16x16x32_bf16(a0h, b1l, acc[0][1], 0, 0, 0);
        acc[1][0] = __builtin_amdgcn_mfma_f32_16x16x32_bf16(a1h, b0l, acc[1][0], 0, 0, 0);
        acc[1][1] = __builtin_amdgcn_mfma_f32_16x16x32_bf16(a1h, b1l, acc[1][1], 0, 0, 0);
        acc[0][0] = __builtin_amdgcn_mfma_f32_16x16x32_bf16(a0h, b0h, acc[0][0], 0, 0, 0);
        acc[0][1] = __builtin_amdgcn_mfma_f32_16x16x32_bf16(a0h, b1h, acc[0][1], 0, 0, 0);
        acc[1][0] = __builtin_amdgcn_mfma_f32_16x16x32_bf16(a1h, b0h, acc[1][0], 0, 0, 0);
        acc[1][1] = __builtin_amdgcn_mfma_f32_16x16x32_bf16(a1h, b1h, acc[1][1], 0, 0, 0);
        __syncthreads();
    }

    #pragma unroll
    for (int tm = 0; tm < 2; tm++)
    #pragma unroll
    for (int tn = 0; tn < 2; tn++)
    #pragma unroll
    for (int r = 0; r < 4; r++) {
        int row = m0 + wm + tm * 16 + quad * 4 + r;
        int col = n0 + wn + tn * 16 + fr;
        atomicAdd(&C[(size_t)row * DMODEL + col], acc[tm][tn][r]);
    }
}

// ---------------------------------------------------------------------------
// Gate: softmax((x @ Wg^T).reshape(n, 16, 2), axis=-1) -> float2 per (n,h)
// ---------------------------------------------------------------------------
__global__ __launch_bounds__(256) void gate_kernel(
    const float* __restrict__ x,
    const float* __restrict__ Wg,
    float2* __restrict__ gate)
{
    __shared__ float gs[32];
    const int n = blockIdx.x;
    const int wave = threadIdx.x >> 6, lane = threadIdx.x & 63;
    #pragma unroll
    for (int jj = 0; jj < 8; jj++) {
        int j = wave * 8 + jj;
        float s = 0.f;
        #pragma unroll
        for (int t = 0; t < 16; t++) {
            int d = lane + (t << 6);
            s += x[n * DMODEL + d] * Wg[j * DMODEL + d];
        }
        #pragma unroll
        for (int off = 32; off; off >>= 1) s += __shfl_xor(s, off);
        if (lane == 0) gs[j] = s;
    }
    __syncthreads();
    if (threadIdx.x < NHEAD) {
        int h = threadIdx.x;
        float a = gs[2 * h], b = gs[2 * h + 1];
        float m = fmaxf(a, b);
        float ea = expf(a - m), eb = expf(b - m);
        float inv = 1.f / (ea + eb);
        gate[n * NHEAD + h] = make_float2(ea * inv, eb * inv);
    }
}

// ---------------------------------------------------------------------------
// k_compress[g][f] = mean over c of K[g*64+c][f]
// ---------------------------------------------------------------------------
__global__ __launch_bounds__(256) void kcompress_kernel(
    const float* __restrict__ K, float* __restrict__ kc)
{
    const int g = blockIdx.x;
    for (int f = threadIdx.x; f < DMODEL; f += 256) {
        float s = 0.f;
        #pragma unroll 8
        for (int c = 0; c < CHUNK; c++) s += K[(size_t)(g * CHUNK + c) * DMODEL + f];
        kc[g * DMODEL + f] = s * (1.0f / CHUNK);
    }
}

// ---------------------------------------------------------------------------
// score + top-2 per (n,h), written TRANSPOSED: idx_t[h*1024 + n].
// Mask: g masked if n >= 64*g. Ties -> lowest index (jax.lax.top_k).
// n >= 960: all -inf -> (0,1).
// ---------------------------------------------------------------------------
__global__ __launch_bounds__(256) void score_top2_kernel(
    const float* __restrict__ Q, const float* __restrict__ kc,
    int2* __restrict__ idx_t)
{
    const int t = blockIdx.x * 256 + threadIdx.x;   // t = n*16 + h
    const int n = t >> 4, h = t & 15;
    float q[HDIM];
    #pragma unroll
    for (int d = 0; d < HDIM; d++) q[d] = Q[(size_t)n * DMODEL + h * HDIM + d];
    float sc[NBLK];
    #pragma unroll
    for (int g = 0; g < NBLK; g++) {
        float s = 0.f;
        #pragma unroll
        for (int d = 0; d < HDIM; d++) s += q[d] * kc[g * DMODEL + h * HDIM + d];
        sc[g] = (n >= (g << 6)) ? -INFINITY : s;
    }
    int i1 = -1; float b1 = -INFINITY;
    #pragma unroll
    for (int g = 0; g < NBLK; g++) if (i1 < 0 || sc[g] > b1) { b1 = sc[g]; i1 = g; }
    int i2 = -1; float b2 = -INFINITY;
    #pragma unroll
    for (int g = 0; g < NBLK; g++) { if (g == i1) continue; if (i2 < 0 || sc[g] > b2) { b2 = sc[g]; i2 = g; } }
    idx_t[(h << 10) | n] = make_int2(i1, i2);
}

// ---------------------------------------------------------------------------
// Intra: causal attention within each 64-chunk. One block per (g,h).
// ---------------------------------------------------------------------------
__global__ __launch_bounds__(256) void intra_kernel(
    const float* __restrict__ Q, const float* __restrict__ K,
    const float* __restrict__ V, float* __restrict__ o_intra)
{
    __shared__ float Qs[64][65], Ks[64][65], Vs[64][65];
    const int g = blockIdx.x >> 4, h = blockIdx.x & 15;
    for (int i = threadIdx.x; i < 64 * 64; i += 256) {
        int r = i >> 6, c = i & 63;
        size_t off = (size_t)(g * CHUNK + r) * DMODEL + h * HDIM + c;
        Qs[r][c] = Q[off]; Ks[r][c] = K[off]; Vs[r][c] = V[off];
    }
    __syncthreads();
    const int wave = threadIdx.x >> 6, lane = threadIdx.x & 63;
    for (int qi = wave; qi < 64; qi += 4) {
        float s = 0.f;
        #pragma unroll 16
        for (int d = 0; d < HDIM; d++) s += Qs[qi][d] * Ks[lane][d];
        s *= 0.125f;
        if (lane > qi) s = -INFINITY;
        float m = s;
        #pragma unroll
        for (int off = 32; off; off >>= 1) m = fmaxf(m, __shfl_xor(m, off));
        float p = expf(s - m);
        float sum = p;
        #pragma unroll
        for (int off = 32; off; off >>= 1) sum += __shfl_xor(sum, off);
        p /= sum;
        float o = 0.f;
        for (int k = 0; k <= qi; k++) {
            float pk = __shfl(p, k);
            o += pk * Vs[k][lane];
        }
        o_intra[(size_t)(g * CHUNK + qi) * DMODEL + h * HDIM + lane] = o;
    }
}

// ---------------------------------------------------------------------------
// Inter partials, flash-style split over blocks. One block per (g,h,seg):
// stage K/V chunk for (g,h) in LDS (coalesced), scan queries n in the segment,
// for those that selected g compute (m, l, unnormalized o) and store.
// ---------------------------------------------------------------------------
__global__ __launch_bounds__(256) void inter_partial_kernel(
    const float* __restrict__ Q, const float* __restrict__ K,
    const float* __restrict__ V, const int2* __restrict__ idx_t,
    float* __restrict__ po, float2* __restrict__ ml)
{
    __shared__ float Ks[64][65], Vs[64][65];
    __shared__ int2 sidx[256];
    const int b = blockIdx.x;
    const int seg = b & 3, gh = b >> 2;
    const int g = gh >> 4, h = gh & 15;

    for (int i = threadIdx.x; i < 64 * 64; i += 256) {
        int r = i >> 6, c = i & 63;
        size_t off = (size_t)(g * CHUNK + r) * DMODEL + h * HDIM + c;
        Ks[r][c] = K[off];
        Vs[r][c] = V[off];
    }
    const int n0 = seg * 256;
    sidx[threadIdx.x] = idx_t[(h << 10) + n0 + threadIdx.x];
    __syncthreads();

    const int wave = threadIdx.x >> 6, lane = threadIdx.x & 63;
    for (int nn = wave; nn < 256; nn += 4) {
        int2 sel = sidx[nn];
        int slot = (sel.x == g) ? 0 : (sel.y == g) ? 1 : -1;
        if (slot < 0) continue;                   // wave-uniform skip
        const int n = n0 + nn;
        const float qv = Q[(size_t)n * DMODEL + h * HDIM + lane];
        float s = 0.f;
        #pragma unroll 16
        for (int d = 0; d < HDIM; d++) s += __shfl(qv, d) * Ks[lane][d];
        s *= 0.125f;
        float m = s;
        #pragma unroll
        for (int off = 32; off; off >>= 1) m = fmaxf(m, __shfl_xor(m, off));
        float e = expf(s - m);
        float l = e;
        #pragma unroll
        for (int off = 32; off; off >>= 1) l += __shfl_xor(l, off);
        float o = 0.f;
        #pragma unroll 16
        for (int k = 0; k < CHUNK; k++) {
            float ek = __shfl(e, k);
            o += ek * Vs[k][lane];
        }
        const int pair = (n << 4) + h;
        po[((size_t)(pair * 2 + slot)) * 64 + lane] = o;
        if (lane == 0) ml[pair * 2 + slot] = make_float2(m, l);
    }
}

// ---------------------------------------------------------------------------
// Combine the 2 partials per (n,h), gated blend with intra, write o into O.
// t = n*1024 + h*64 + d  (== pair*64 + d)
// ---------------------------------------------------------------------------
__global__ __launch_bounds__(256) void inter_combine_kernel(
    const float* __restrict__ po, const float2* __restrict__ ml,
    const float2* __restrict__ gate, const float* __restrict__ o_intra,
    float* __restrict__ O)
{
    const int t = blockIdx.x * 256 + threadIdx.x;
    const int pair = t >> 6, d = t & 63;
    const float2 m0 = ml[pair * 2], m1 = ml[pair * 2 + 1];
    const float m = fmaxf(m0.x, m1.x);
    const float w0 = expf(m0.x - m), w1 = expf(m1.x - m);
    const float denom = m0.y * w0 + m1.y * w1;
    const float p0 = po[(size_t)pair * 128 + d];
    const float p1 = po[(size_t)pair * 128 + 64 + d];
    const float o_int = (p0 * w0 + p1 * w1) / denom;
    const float2 gt = gate[pair];
    O[t] = gt.x * o_int + gt.y * o_intra[t];
}

// ---------------------------------------------------------------------------
extern "C" void kernel_launch(void* const* d_in, const int* in_sizes, int n_in,
                              void* d_out, int out_size, void* d_ws, size_t ws_size,
                              hipStream_t stream)
{
    const float* x  = (const float*)d_in[0];
    const float* Wq = (const float*)d_in[1];
    const float* Wk = (const float*)d_in[2];
    const float* Wv = (const float*)d_in[3];
    const float* Wg = (const float*)d_in[4];
    const float* Wo = (const float*)d_in[5];

    // workspace layout (~24.6 MB)
    float* Q       = (float*)d_ws;                    // 4 MB
    float* K       = Q + (1 << 20);                   // 4 MB
    float* V       = K + (1 << 20);                   // 4 MB
    float* o_intra = V + (1 << 20);                   // 4 MB
    float* kc      = o_intra + (1 << 20);             // 64 KB
    float2* gate   = (float2*)(kc + NBLK * DMODEL);   // 128 KB
    int2* idx_t    = (int2*)(gate + NTOK * NHEAD);    // 128 KB
    float2* ml     = (float2*)(idx_t + NTOK * NHEAD); // 256 KB
    float* po      = (float*)(ml + NTOK * NHEAD * 2); // 8 MB

    dim3 gqkv(48, 16);
    gemm_qkv<<<gqkv, 256, 0, stream>>>(x, Wq, Wk, Wv, Q, K, V);
    gate_kernel<<<NTOK, 256, 0, stream>>>(x, Wg, gate);
    kcompress_kernel<<<NBLK, 256, 0, stream>>>(K, kc);
    score_top2_kernel<<<NTOK * NHEAD / 256, 256, 0, stream>>>(Q, kc, idx_t);
    intra_kernel<<<NBLK * NHEAD, 256, 0, stream>>>(Q, K, V, o_intra);
    inter_partial_kernel<<<NBLK * NHEAD * 4, 256, 0, stream>>>(Q, K, V, idx_t, po, ml);
    // combine writes blended o in-place over Q (Q fully consumed above)
    inter_combine_kernel<<<NTOK * DMODEL / 256, 256, 0, stream>>>(po, ml, gate, o_intra, Q);

    hipMemsetAsync(d_out, 0, (size_t)NTOK * DMODEL * sizeof(float), stream);
    dim3 gwo(16, 16, 2);
    gemm_wo_splitk<<<gwo, 256, 0, stream>>>(Q, Wo, (float*)d_out);
}

// Round 6
// 278.879 us; speedup vs baseline: 1.3700x; 1.2775x over previous
//
#include <hip/hip_runtime.h>
#include <hip/hip_bf16.h>
#include <math.h>

// Problem: B=1, N=1024, D=1024, H=16, C=64, TOPK=2, HD=64, G=16
// Inputs (float32): x[1024,1024], Wq[1024,1024], Wk, Wv, Wg[32,1024], Wo[1024,1024]
// Output (float32): [1024,1024]
//
// Numerics: bf16x2 split MFMA (Ah*Bh + Ah*Bl + Al*Bh, f32 accumulate) for all
// big GEMMs; hi/lo split in-register during LDS staging. Attention exact f32.
// Inter attention: per-(n,h)-wave (balanced, high occupancy) with K accessed
// through a per-head transpose Kt[h][d][n] so lane reads are coalesced.

typedef __attribute__((ext_vector_type(8))) short short8;   // 8 bf16 = 4 VGPRs
typedef __attribute__((ext_vector_type(4))) float f32x4;

#define NTOK 1024
#define DMODEL 1024
#define NHEAD 16
#define HDIM 64
#define CHUNK 64
#define NBLK 16

// ---------------------------------------------------------------------------
// helper: load 8 f32, split into hi/lo bf16 short8
// ---------------------------------------------------------------------------
__device__ inline void split8(const float* p, short8& hi, short8& lo)
{
    float4 v0 = *(const float4*)p;
    float4 v1 = *(const float4*)(p + 4);
    float vv[8] = {v0.x, v0.y, v0.z, v0.w, v1.x, v1.y, v1.z, v1.w};
    union { short8 s; __hip_bfloat16 b[8]; } h, l;
    #pragma unroll
    for (int j = 0; j < 8; j++) {
        h.b[j] = __float2bfloat16(vv[j]);
        l.b[j] = __float2bfloat16(vv[j] - __bfloat162float(h.b[j]));
    }
    hi = h.s; lo = l.s;
}

// ---------------------------------------------------------------------------
// QKV fused: blockIdx.x in [0,48): widx=x>>4 selects Wq/Wk/Wv + output.
// ---------------------------------------------------------------------------
__global__ __launch_bounds__(256) void gemm_qkv(
    const float* __restrict__ x,
    const float* __restrict__ Wq, const float* __restrict__ Wk,
    const float* __restrict__ Wv,
    float* __restrict__ Q, float* __restrict__ K, float* __restrict__ V)
{
    __shared__ alignas(16) __hip_bfloat16 Ash[64][40];
    __shared__ alignas(16) __hip_bfloat16 Asl[64][40];
    __shared__ alignas(16) __hip_bfloat16 Bsh[64][40];
    __shared__ alignas(16) __hip_bfloat16 Bsl[64][40];

    const int widx = blockIdx.x >> 4;
    const float* __restrict__ B = (widx == 0) ? Wq : (widx == 1) ? Wk : Wv;
    float* __restrict__ C = (widx == 0) ? Q : (widx == 1) ? K : V;
    const int n0 = (blockIdx.x & 15) * 64;
    const int m0 = blockIdx.y * 64;

    const int tid  = threadIdx.x;
    const int wave = tid >> 6;
    const int lane = tid & 63;
    const int lr = tid >> 2;
    const int lc = (tid & 3) * 8;
    const int wm = (wave >> 1) * 32;
    const int wn = (wave & 1) * 32;
    const int fr = lane & 15;
    const int quad = lane >> 4;

    f32x4 acc[2][2] = {};

    for (int k0 = 0; k0 < DMODEL; k0 += 32) {
        short8 ah, al, bh, bl;
        split8(x + (size_t)(m0 + lr) * DMODEL + k0 + lc, ah, al);
        split8(B + (size_t)(n0 + lr) * DMODEL + k0 + lc, bh, bl);
        *(short8*)(&Ash[lr][lc]) = ah;
        *(short8*)(&Asl[lr][lc]) = al;
        *(short8*)(&Bsh[lr][lc]) = bh;
        *(short8*)(&Bsl[lr][lc]) = bl;
        __syncthreads();

        short8 a0h = *(const short8*)(&Ash[wm + fr][quad * 8]);
        short8 a1h = *(const short8*)(&Ash[wm + 16 + fr][quad * 8]);
        short8 a0l = *(const short8*)(&Asl[wm + fr][quad * 8]);
        short8 a1l = *(const short8*)(&Asl[wm + 16 + fr][quad * 8]);
        short8 b0h = *(const short8*)(&Bsh[wn + fr][quad * 8]);
        short8 b1h = *(const short8*)(&Bsh[wn + 16 + fr][quad * 8]);
        short8 b0l = *(const short8*)(&Bsl[wn + fr][quad * 8]);
        short8 b1l = *(const short8*)(&Bsl[wn + 16 + fr][quad * 8]);

        acc[0][0] = __builtin_amdgcn_mfma_f32_16x16x32_bf16(a0l, b0h, acc[0][0], 0, 0, 0);
        acc[0][1] = __builtin_amdgcn_mfma_f32_16x16x32_bf16(a0l, b1h, acc[0][1], 0, 0, 0);
        acc[1][0] = __builtin_amdgcn_mfma_f32_16x16x32_bf16(a1l, b0h, acc[1][0], 0, 0, 0);
        acc[1][1] = __builtin_amdgcn_mfma_f32_16x16x32_bf16(a1l, b1h, acc[1][1], 0, 0, 0);
        acc[0][0] = __builtin_amdgcn_mfma_f32_16x16x32_bf16(a0h, b0l, acc[0][0], 0, 0, 0);
        acc[0][1] = __builtin_amdgcn_mfma_f32_16x16x32_bf16(a0h, b1l, acc[0][1], 0, 0, 0);
        acc[1][0] = __builtin_amdgcn_mfma_f32_16x16x32_bf16(a1h, b0l, acc[1][0], 0, 0, 0);
        acc[1][1] = __builtin_amdgcn_mfma_f32_16x16x32_bf16(a1h, b1l, acc[1][1], 0, 0, 0);
        acc[0][0] = __builtin_amdgcn_mfma_f32_16x16x32_bf16(a0h, b0h, acc[0][0], 0, 0, 0);
        acc[0][1] = __builtin_amdgcn_mfma_f32_16x16x32_bf16(a0h, b1h, acc[0][1], 0, 0, 0);
        acc[1][0] = __builtin_amdgcn_mfma_f32_16x16x32_bf16(a1h, b0h, acc[1][0], 0, 0, 0);
        acc[1][1] = __builtin_amdgcn_mfma_f32_16x16x32_bf16(a1h, b1h, acc[1][1], 0, 0, 0);
        __syncthreads();
    }

    #pragma unroll
    for (int tm = 0; tm < 2; tm++)
    #pragma unroll
    for (int tn = 0; tn < 2; tn++)
    #pragma unroll
    for (int r = 0; r < 4; r++) {
        int row = m0 + wm + tm * 16 + quad * 4 + r;
        int col = n0 + wn + tn * 16 + fr;
        C[(size_t)row * DMODEL + col] = acc[tm][tn][r];
    }
}

// ---------------------------------------------------------------------------
// Wo GEMM, split-K=2: blockIdx.z selects K-half; atomicAdd into zeroed C.
// ---------------------------------------------------------------------------
__global__ __launch_bounds__(256) void gemm_wo_splitk(
    const float* __restrict__ A, const float* __restrict__ B,
    float* __restrict__ C)
{
    __shared__ alignas(16) __hip_bfloat16 Ash[64][40];
    __shared__ alignas(16) __hip_bfloat16 Asl[64][40];
    __shared__ alignas(16) __hip_bfloat16 Bsh[64][40];
    __shared__ alignas(16) __hip_bfloat16 Bsl[64][40];

    const int n0 = blockIdx.x * 64;
    const int m0 = blockIdx.y * 64;
    const int kbeg = blockIdx.z * (DMODEL / 2);
    const int kend = kbeg + (DMODEL / 2);

    const int tid  = threadIdx.x;
    const int wave = tid >> 6;
    const int lane = tid & 63;
    const int lr = tid >> 2;
    const int lc = (tid & 3) * 8;
    const int wm = (wave >> 1) * 32;
    const int wn = (wave & 1) * 32;
    const int fr = lane & 15;
    const int quad = lane >> 4;

    f32x4 acc[2][2] = {};

    for (int k0 = kbeg; k0 < kend; k0 += 32) {
        short8 ah, al, bh, bl;
        split8(A + (size_t)(m0 + lr) * DMODEL + k0 + lc, ah, al);
        split8(B + (size_t)(n0 + lr) * DMODEL + k0 + lc, bh, bl);
        *(short8*)(&Ash[lr][lc]) = ah;
        *(short8*)(&Asl[lr][lc]) = al;
        *(short8*)(&Bsh[lr][lc]) = bh;
        *(short8*)(&Bsl[lr][lc]) = bl;
        __syncthreads();

        short8 a0h = *(const short8*)(&Ash[wm + fr][quad * 8]);
        short8 a1h = *(const short8*)(&Ash[wm + 16 + fr][quad * 8]);
        short8 a0l = *(const short8*)(&Asl[wm + fr][quad * 8]);
        short8 a1l = *(const short8*)(&Asl[wm + 16 + fr][quad * 8]);
        short8 b0h = *(const short8*)(&Bsh[wn + fr][quad * 8]);
        short8 b1h = *(const short8*)(&Bsh[wn + 16 + fr][quad * 8]);
        short8 b0l = *(const short8*)(&Bsl[wn + fr][quad * 8]);
        short8 b1l = *(const short8*)(&Bsl[wn + 16 + fr][quad * 8]);

        acc[0][0] = __builtin_amdgcn_mfma_f32_16x16x32_bf16(a0l, b0h, acc[0][0], 0, 0, 0);
        acc[0][1] = __builtin_amdgcn_mfma_f32_16x16x32_bf16(a0l, b1h, acc[0][1], 0, 0, 0);
        acc[1][0] = __builtin_amdgcn_mfma_f32_16x16x32_bf16(a1l, b0h, acc[1][0], 0, 0, 0);
        acc[1][1] = __builtin_amdgcn_mfma_f32_16x16x32_bf16(a1l, b1h, acc[1][1], 0, 0, 0);
        acc[0][0] = __builtin_amdgcn_mfma_f32_16x16x32_bf16(a0h, b0l, acc[0][0], 0, 0, 0);
        acc[0][1] = __builtin_amdgcn_mfma_f32_16x16x32_bf16(a0h, b1l, acc[0][1], 0, 0, 0);
        acc[1][0] = __builtin_amdgcn_mfma_f32_16x16x32_bf16(a1h, b0l, acc[1][0], 0, 0, 0);
        acc[1][1] = __builtin_amdgcn_mfma_f32_16x16x32_bf16(a1h, b1l, acc[1][1], 0, 0, 0);
        acc[0][0] = __builtin_amdgcn_mfma_f32_16x16x32_bf16(a0h, b0h, acc[0][0], 0, 0, 0);
        acc[0][1] = __builtin_amdgcn_mfma_f32_16x16x32_bf16(a0h, b1h, acc[0][1], 0, 0, 0);
        acc[1][0] = __builtin_amdgcn_mfma_f32_16x16x32_bf16(a1h, b0h, acc[1][0], 0, 0, 0);
        acc[1][1] = __builtin_amdgcn_mfma_f32_16x16x32_bf16(a1h, b1h, acc[1][1], 0, 0, 0);
        __syncthreads();
    }

    #pragma unroll
    for (int tm = 0; tm < 2; tm++)
    #pragma unroll
    for (int tn = 0; tn < 2; tn++)
    #pragma unroll
    for (int r = 0; r < 4; r++) {
        int row = m0 + wm + tm * 16 + quad * 4 + r;
        int col = n0 + wn + tn * 16 + fr;
        atomicAdd(&C[(size_t)row * DMODEL + col], acc[tm][tn][r]);
    }
}

// ---------------------------------------------------------------------------
// Gate: softmax((x @ Wg^T).reshape(n, 16, 2), axis=-1) -> float2 per (n,h)
// ---------------------------------------------------------------------------
__global__ __launch_bounds__(256) void gate_kernel(
    const float* __restrict__ x,
    const float* __restrict__ Wg,
    float2* __restrict__ gate)
{
    __shared__ float gs[32];
    const int n = blockIdx.x;
    const int wave = threadIdx.x >> 6, lane = threadIdx.x & 63;
    #pragma unroll
    for (int jj = 0; jj < 8; jj++) {
        int j = wave * 8 + jj;
        float s = 0.f;
        #pragma unroll
        for (int t = 0; t < 16; t++) {
            int d = lane + (t << 6);
            s += x[n * DMODEL + d] * Wg[j * DMODEL + d];
        }
        #pragma unroll
        for (int off = 32; off; off >>= 1) s += __shfl_xor(s, off);
        if (lane == 0) gs[j] = s;
    }
    __syncthreads();
    if (threadIdx.x < NHEAD) {
        int h = threadIdx.x;
        float a = gs[2 * h], b = gs[2 * h + 1];
        float m = fmaxf(a, b);
        float ea = expf(a - m), eb = expf(b - m);
        float inv = 1.f / (ea + eb);
        gate[n * NHEAD + h] = make_float2(ea * inv, eb * inv);
    }
}

// ---------------------------------------------------------------------------
// k_compress[g][f] = mean over c of K[g*64+c][f]
// ---------------------------------------------------------------------------
__global__ __launch_bounds__(256) void kcompress_kernel(
    const float* __restrict__ K, float* __restrict__ kc)
{
    const int g = blockIdx.x;
    for (int f = threadIdx.x; f < DMODEL; f += 256) {
        float s = 0.f;
        #pragma unroll 8
        for (int c = 0; c < CHUNK; c++) s += K[(size_t)(g * CHUNK + c) * DMODEL + f];
        kc[g * DMODEL + f] = s * (1.0f / CHUNK);
    }
}

// ---------------------------------------------------------------------------
// Per-head transpose: Kt[(h*64+d)*1024 + n] = K[n*1024 + h*64 + d]
// One block per (h, 64-row n-tile); LDS-staged, coalesced both directions.
// ---------------------------------------------------------------------------
__global__ __launch_bounds__(256) void transpose_k_kernel(
    const float* __restrict__ K, float* __restrict__ Kt)
{
    __shared__ float T[64][65];
    const int h = blockIdx.x & 15;
    const int n0 = (blockIdx.x >> 4) * 64;
    for (int i = threadIdx.x; i < 64 * 64; i += 256) {
        int r = i >> 6, d = i & 63;
        T[r][d] = K[(size_t)(n0 + r) * DMODEL + h * HDIM + d];
    }
    __syncthreads();
    for (int i = threadIdx.x; i < 64 * 64; i += 256) {
        int d = i >> 6, nn = i & 63;
        Kt[(size_t)(h * HDIM + d) * NTOK + n0 + nn] = T[nn][d];
    }
}

// ---------------------------------------------------------------------------
// score + top-2 per (n,h), written TRANSPOSED: idx_t[h*1024 + n].
// Mask: g masked if n >= 64*g. Ties -> lowest index (jax.lax.top_k).
// n >= 960: all -inf -> (0,1).
// ---------------------------------------------------------------------------
__global__ __launch_bounds__(256) void score_top2_kernel(
    const float* __restrict__ Q, const float* __restrict__ kc,
    int2* __restrict__ idx_t)
{
    const int t = blockIdx.x * 256 + threadIdx.x;   // t = n*16 + h
    const int n = t >> 4, h = t & 15;
    float q[HDIM];
    #pragma unroll
    for (int d = 0; d < HDIM; d++) q[d] = Q[(size_t)n * DMODEL + h * HDIM + d];
    float sc[NBLK];
    #pragma unroll
    for (int g = 0; g < NBLK; g++) {
        float s = 0.f;
        #pragma unroll
        for (int d = 0; d < HDIM; d++) s += q[d] * kc[g * DMODEL + h * HDIM + d];
        sc[g] = (n >= (g << 6)) ? -INFINITY : s;
    }
    int i1 = -1; float b1 = -INFINITY;
    #pragma unroll
    for (int g = 0; g < NBLK; g++) if (i1 < 0 || sc[g] > b1) { b1 = sc[g]; i1 = g; }
    int i2 = -1; float b2 = -INFINITY;
    #pragma unroll
    for (int g = 0; g < NBLK; g++) { if (g == i1) continue; if (i2 < 0 || sc[g] > b2) { b2 = sc[g]; i2 = g; } }
    idx_t[(h << 10) | n] = make_int2(i1, i2);
}

// ---------------------------------------------------------------------------
// Intra: causal attention within each 64-chunk. One block per (g,h).
// ---------------------------------------------------------------------------
__global__ __launch_bounds__(256) void intra_kernel(
    const float* __restrict__ Q, const float* __restrict__ K,
    const float* __restrict__ V, float* __restrict__ o_intra)
{
    __shared__ float Qs[64][65], Ks[64][65], Vs[64][65];
    const int g = blockIdx.x >> 4, h = blockIdx.x & 15;
    for (int i = threadIdx.x; i < 64 * 64; i += 256) {
        int r = i >> 6, c = i & 63;
        size_t off = (size_t)(g * CHUNK + r) * DMODEL + h * HDIM + c;
        Qs[r][c] = Q[off]; Ks[r][c] = K[off]; Vs[r][c] = V[off];
    }
    __syncthreads();
    const int wave = threadIdx.x >> 6, lane = threadIdx.x & 63;
    for (int qi = wave; qi < 64; qi += 4) {
        float s = 0.f;
        #pragma unroll 16
        for (int d = 0; d < HDIM; d++) s += Qs[qi][d] * Ks[lane][d];
        s *= 0.125f;
        if (lane > qi) s = -INFINITY;
        float m = s;
        #pragma unroll
        for (int off = 32; off; off >>= 1) m = fmaxf(m, __shfl_xor(m, off));
        float p = expf(s - m);
        float sum = p;
        #pragma unroll
        for (int off = 32; off; off >>= 1) sum += __shfl_xor(sum, off);
        p /= sum;
        float o = 0.f;
        for (int k = 0; k <= qi; k++) {
            float pk = __shfl(p, k);
            o += pk * Vs[k][lane];
        }
        o_intra[(size_t)(g * CHUNK + qi) * DMODEL + h * HDIM + lane] = o;
    }
}

// ---------------------------------------------------------------------------
// Inter attention over 2 selected blocks (128 keys) + gated blend with intra.
// One wave per (n,h); K via per-head transpose Kt (coalesced), V coalesced.
// Writes blended o (f32) IN-PLACE over Q (each wave reads its Q elem first).
// ---------------------------------------------------------------------------
__global__ __launch_bounds__(256) void inter_blend_kernel(
    float* __restrict__ Q, const float* __restrict__ Kt,
    const float* __restrict__ V, const int2* __restrict__ idx_t,
    const float2* __restrict__ gate, const float* __restrict__ o_intra)
{
    const int wave = threadIdx.x >> 6, lane = threadIdx.x & 63;
    const int gw = blockIdx.x * 4 + wave;   // = n*16 + h
    const int n = gw >> 4, h = gw & 15;
    const int2 sel = idx_t[(h << 10) | n];
    const int r1 = sel.x * CHUNK, r2 = sel.y * CHUNK;

    const float qreg = Q[(size_t)n * DMODEL + h * HDIM + lane];
    const float* Kth = Kt + (size_t)h * HDIM * NTOK;
    float s0 = 0.f, s1 = 0.f;
    #pragma unroll 8
    for (int d = 0; d < HDIM; d++) {
        float qd = __shfl(qreg, d);
        const float* row = Kth + (size_t)d * NTOK;
        s0 += qd * row[r1 + lane];     // coalesced: lanes -> consecutive n
        s1 += qd * row[r2 + lane];
    }
    s0 *= 0.125f; s1 *= 0.125f;
    float m = fmaxf(s0, s1);
    #pragma unroll
    for (int off = 32; off; off >>= 1) m = fmaxf(m, __shfl_xor(m, off));
    float e0 = expf(s0 - m), e1 = expf(s1 - m);
    float sum = e0 + e1;
    #pragma unroll
    for (int off = 32; off; off >>= 1) sum += __shfl_xor(sum, off);
    float inv = 1.f / sum;
    float p0 = e0 * inv, p1 = e1 * inv;

    const float* Vh = V + h * HDIM;
    float o = 0.f;
    #pragma unroll 8
    for (int k = 0; k < CHUNK; k++) {
        float pa = __shfl(p0, k), pb = __shfl(p1, k);
        o += pa * Vh[(size_t)(r1 + k) * DMODEL + lane];   // coalesced
        o += pb * Vh[(size_t)(r2 + k) * DMODEL + lane];
    }
    const float2 gt = gate[gw];
    const float oi = o_intra[(size_t)n * DMODEL + h * HDIM + lane];
    Q[(size_t)n * DMODEL + h * HDIM + lane] = gt.x * o + gt.y * oi;
}

// ---------------------------------------------------------------------------
extern "C" void kernel_launch(void* const* d_in, const int* in_sizes, int n_in,
                              void* d_out, int out_size, void* d_ws, size_t ws_size,
                              hipStream_t stream)
{
    const float* x  = (const float*)d_in[0];
    const float* Wq = (const float*)d_in[1];
    const float* Wk = (const float*)d_in[2];
    const float* Wv = (const float*)d_in[3];
    const float* Wg = (const float*)d_in[4];
    const float* Wo = (const float*)d_in[5];

    // workspace layout (~20.6 MB)
    float* Q       = (float*)d_ws;                    // 4 MB
    float* K       = Q + (1 << 20);                   // 4 MB
    float* V       = K + (1 << 20);                   // 4 MB
    float* o_intra = V + (1 << 20);                   // 4 MB
    float* Kt      = o_intra + (1 << 20);             // 4 MB (per-head transpose)
    float* kc      = Kt + (1 << 20);                  // 64 KB
    float2* gate   = (float2*)(kc + NBLK * DMODEL);   // 128 KB
    int2* idx_t    = (int2*)(gate + NTOK * NHEAD);    // 128 KB

    dim3 gqkv(48, 16);
    gemm_qkv<<<gqkv, 256, 0, stream>>>(x, Wq, Wk, Wv, Q, K, V);
    gate_kernel<<<NTOK, 256, 0, stream>>>(x, Wg, gate);
    kcompress_kernel<<<NBLK, 256, 0, stream>>>(K, kc);
    transpose_k_kernel<<<256, 256, 0, stream>>>(K, Kt);
    score_top2_kernel<<<NTOK * NHEAD / 256, 256, 0, stream>>>(Q, kc, idx_t);
    intra_kernel<<<NBLK * NHEAD, 256, 0, stream>>>(Q, K, V, o_intra);
    // writes blended o in-place over Q
    inter_blend_kernel<<<NTOK * NHEAD / 4, 256, 0, stream>>>(Q, Kt, V, idx_t, gate, o_intra);

    hipMemsetAsync(d_out, 0, (size_t)NTOK * DMODEL * sizeof(float), stream);
    dim3 gwo(16, 16, 2);
    gemm_wo_splitk<<<gwo, 256, 0, stream>>>(Q, Wo, (float*)d_out);
}

// Round 7
// 261.324 us; speedup vs baseline: 1.4621x; 1.0672x over previous
//
#include <hip/hip_runtime.h>
#include <hip/hip_bf16.h>
#include <math.h>

// Problem: B=1, N=1024, D=1024, H=16, C=64, TOPK=2, HD=64, G=16
// Inputs (float32): x[1024,1024], Wq[1024,1024], Wk, Wv, Wg[32,1024], Wo[1024,1024]
// Output (float32): [1024,1024]
//
// Numerics: bf16x2 split MFMA (Ah*Bh + Ah*Bl + Al*Bh, f32 accumulate) for all
// big GEMMs; hi/lo split in-register during LDS staging. Attention exact f32.
// Attention fully fused: one wave per (n,h) computes inter (2 selected blocks,
// K via per-head transpose Kt for coalescing) + causal intra (own chunk) +
// gated blend, written in-place over Q.

typedef __attribute__((ext_vector_type(8))) short short8;   // 8 bf16 = 4 VGPRs
typedef __attribute__((ext_vector_type(4))) float f32x4;

#define NTOK 1024
#define DMODEL 1024
#define NHEAD 16
#define HDIM 64
#define CHUNK 64
#define NBLK 16

// ---------------------------------------------------------------------------
// helper: load 8 f32, split into hi/lo bf16 short8
// ---------------------------------------------------------------------------
__device__ inline void split8(const float* p, short8& hi, short8& lo)
{
    float4 v0 = *(const float4*)p;
    float4 v1 = *(const float4*)(p + 4);
    float vv[8] = {v0.x, v0.y, v0.z, v0.w, v1.x, v1.y, v1.z, v1.w};
    union { short8 s; __hip_bfloat16 b[8]; } h, l;
    #pragma unroll
    for (int j = 0; j < 8; j++) {
        h.b[j] = __float2bfloat16(vv[j]);
        l.b[j] = __float2bfloat16(vv[j] - __bfloat162float(h.b[j]));
    }
    hi = h.s; lo = l.s;
}

// ---------------------------------------------------------------------------
// QKV fused: blockIdx.x in [0,48): widx=x>>4 selects Wq/Wk/Wv + output.
// ---------------------------------------------------------------------------
__global__ __launch_bounds__(256) void gemm_qkv(
    const float* __restrict__ x,
    const float* __restrict__ Wq, const float* __restrict__ Wk,
    const float* __restrict__ Wv,
    float* __restrict__ Q, float* __restrict__ K, float* __restrict__ V)
{
    __shared__ alignas(16) __hip_bfloat16 Ash[64][40];
    __shared__ alignas(16) __hip_bfloat16 Asl[64][40];
    __shared__ alignas(16) __hip_bfloat16 Bsh[64][40];
    __shared__ alignas(16) __hip_bfloat16 Bsl[64][40];

    const int widx = blockIdx.x >> 4;
    const float* __restrict__ B = (widx == 0) ? Wq : (widx == 1) ? Wk : Wv;
    float* __restrict__ C = (widx == 0) ? Q : (widx == 1) ? K : V;
    const int n0 = (blockIdx.x & 15) * 64;
    const int m0 = blockIdx.y * 64;

    const int tid  = threadIdx.x;
    const int wave = tid >> 6;
    const int lane = tid & 63;
    const int lr = tid >> 2;
    const int lc = (tid & 3) * 8;
    const int wm = (wave >> 1) * 32;
    const int wn = (wave & 1) * 32;
    const int fr = lane & 15;
    const int quad = lane >> 4;

    f32x4 acc[2][2] = {};

    for (int k0 = 0; k0 < DMODEL; k0 += 32) {
        short8 ah, al, bh, bl;
        split8(x + (size_t)(m0 + lr) * DMODEL + k0 + lc, ah, al);
        split8(B + (size_t)(n0 + lr) * DMODEL + k0 + lc, bh, bl);
        *(short8*)(&Ash[lr][lc]) = ah;
        *(short8*)(&Asl[lr][lc]) = al;
        *(short8*)(&Bsh[lr][lc]) = bh;
        *(short8*)(&Bsl[lr][lc]) = bl;
        __syncthreads();

        short8 a0h = *(const short8*)(&Ash[wm + fr][quad * 8]);
        short8 a1h = *(const short8*)(&Ash[wm + 16 + fr][quad * 8]);
        short8 a0l = *(const short8*)(&Asl[wm + fr][quad * 8]);
        short8 a1l = *(const short8*)(&Asl[wm + 16 + fr][quad * 8]);
        short8 b0h = *(const short8*)(&Bsh[wn + fr][quad * 8]);
        short8 b1h = *(const short8*)(&Bsh[wn + 16 + fr][quad * 8]);
        short8 b0l = *(const short8*)(&Bsl[wn + fr][quad * 8]);
        short8 b1l = *(const short8*)(&Bsl[wn + 16 + fr][quad * 8]);

        acc[0][0] = __builtin_amdgcn_mfma_f32_16x16x32_bf16(a0l, b0h, acc[0][0], 0, 0, 0);
        acc[0][1] = __builtin_amdgcn_mfma_f32_16x16x32_bf16(a0l, b1h, acc[0][1], 0, 0, 0);
        acc[1][0] = __builtin_amdgcn_mfma_f32_16x16x32_bf16(a1l, b0h, acc[1][0], 0, 0, 0);
        acc[1][1] = __builtin_amdgcn_mfma_f32_16x16x32_bf16(a1l, b1h, acc[1][1], 0, 0, 0);
        acc[0][0] = __builtin_amdgcn_mfma_f32_16x16x32_bf16(a0h, b0l, acc[0][0], 0, 0, 0);
        acc[0][1] = __builtin_amdgcn_mfma_f32_16x16x32_bf16(a0h, b1l, acc[0][1], 0, 0, 0);
        acc[1][0] = __builtin_amdgcn_mfma_f32_16x16x32_bf16(a1h, b0l, acc[1][0], 0, 0, 0);
        acc[1][1] = __builtin_amdgcn_mfma_f32_16x16x32_bf16(a1h, b1l, acc[1][1], 0, 0, 0);
        acc[0][0] = __builtin_amdgcn_mfma_f32_16x16x32_bf16(a0h, b0h, acc[0][0], 0, 0, 0);
        acc[0][1] = __builtin_amdgcn_mfma_f32_16x16x32_bf16(a0h, b1h, acc[0][1], 0, 0, 0);
        acc[1][0] = __builtin_amdgcn_mfma_f32_16x16x32_bf16(a1h, b0h, acc[1][0], 0, 0, 0);
        acc[1][1] = __builtin_amdgcn_mfma_f32_16x16x32_bf16(a1h, b1h, acc[1][1], 0, 0, 0);
        __syncthreads();
    }

    #pragma unroll
    for (int tm = 0; tm < 2; tm++)
    #pragma unroll
    for (int tn = 0; tn < 2; tn++)
    #pragma unroll
    for (int r = 0; r < 4; r++) {
        int row = m0 + wm + tm * 16 + quad * 4 + r;
        int col = n0 + wn + tn * 16 + fr;
        C[(size_t)row * DMODEL + col] = acc[tm][tn][r];
    }
}

// ---------------------------------------------------------------------------
// Wo GEMM, split-K=2: blockIdx.z selects K-half; atomicAdd into zeroed C.
// ---------------------------------------------------------------------------
__global__ __launch_bounds__(256) void gemm_wo_splitk(
    const float* __restrict__ A, const float* __restrict__ B,
    float* __restrict__ C)
{
    __shared__ alignas(16) __hip_bfloat16 Ash[64][40];
    __shared__ alignas(16) __hip_bfloat16 Asl[64][40];
    __shared__ alignas(16) __hip_bfloat16 Bsh[64][40];
    __shared__ alignas(16) __hip_bfloat16 Bsl[64][40];

    const int n0 = blockIdx.x * 64;
    const int m0 = blockIdx.y * 64;
    const int kbeg = blockIdx.z * (DMODEL / 2);
    const int kend = kbeg + (DMODEL / 2);

    const int tid  = threadIdx.x;
    const int wave = tid >> 6;
    const int lane = tid & 63;
    const int lr = tid >> 2;
    const int lc = (tid & 3) * 8;
    const int wm = (wave >> 1) * 32;
    const int wn = (wave & 1) * 32;
    const int fr = lane & 15;
    const int quad = lane >> 4;

    f32x4 acc[2][2] = {};

    for (int k0 = kbeg; k0 < kend; k0 += 32) {
        short8 ah, al, bh, bl;
        split8(A + (size_t)(m0 + lr) * DMODEL + k0 + lc, ah, al);
        split8(B + (size_t)(n0 + lr) * DMODEL + k0 + lc, bh, bl);
        *(short8*)(&Ash[lr][lc]) = ah;
        *(short8*)(&Asl[lr][lc]) = al;
        *(short8*)(&Bsh[lr][lc]) = bh;
        *(short8*)(&Bsl[lr][lc]) = bl;
        __syncthreads();

        short8 a0h = *(const short8*)(&Ash[wm + fr][quad * 8]);
        short8 a1h = *(const short8*)(&Ash[wm + 16 + fr][quad * 8]);
        short8 a0l = *(const short8*)(&Asl[wm + fr][quad * 8]);
        short8 a1l = *(const short8*)(&Asl[wm + 16 + fr][quad * 8]);
        short8 b0h = *(const short8*)(&Bsh[wn + fr][quad * 8]);
        short8 b1h = *(const short8*)(&Bsh[wn + 16 + fr][quad * 8]);
        short8 b0l = *(const short8*)(&Bsl[wn + fr][quad * 8]);
        short8 b1l = *(const short8*)(&Bsl[wn + 16 + fr][quad * 8]);

        acc[0][0] = __builtin_amdgcn_mfma_f32_16x16x32_bf16(a0l, b0h, acc[0][0], 0, 0, 0);
        acc[0][1] = __builtin_amdgcn_mfma_f32_16x16x32_bf16(a0l, b1h, acc[0][1], 0, 0, 0);
        acc[1][0] = __builtin_amdgcn_mfma_f32_16x16x32_bf16(a1l, b0h, acc[1][0], 0, 0, 0);
        acc[1][1] = __builtin_amdgcn_mfma_f32_16x16x32_bf16(a1l, b1h, acc[1][1], 0, 0, 0);
        acc[0][0] = __builtin_amdgcn_mfma_f32_16x16x32_bf16(a0h, b0l, acc[0][0], 0, 0, 0);
        acc[0][1] = __builtin_amdgcn_mfma_f32_16x16x32_bf16(a0h, b1l, acc[0][1], 0, 0, 0);
        acc[1][0] = __builtin_amdgcn_mfma_f32_16x16x32_bf16(a1h, b0l, acc[1][0], 0, 0, 0);
        acc[1][1] = __builtin_amdgcn_mfma_f32_16x16x32_bf16(a1h, b1l, acc[1][1], 0, 0, 0);
        acc[0][0] = __builtin_amdgcn_mfma_f32_16x16x32_bf16(a0h, b0h, acc[0][0], 0, 0, 0);
        acc[0][1] = __builtin_amdgcn_mfma_f32_16x16x32_bf16(a0h, b1h, acc[0][1], 0, 0, 0);
        acc[1][0] = __builtin_amdgcn_mfma_f32_16x16x32_bf16(a1h, b0h, acc[1][0], 0, 0, 0);
        acc[1][1] = __builtin_amdgcn_mfma_f32_16x16x32_bf16(a1h, b1h, acc[1][1], 0, 0, 0);
        __syncthreads();
    }

    #pragma unroll
    for (int tm = 0; tm < 2; tm++)
    #pragma unroll
    for (int tn = 0; tn < 2; tn++)
    #pragma unroll
    for (int r = 0; r < 4; r++) {
        int row = m0 + wm + tm * 16 + quad * 4 + r;
        int col = n0 + wn + tn * 16 + fr;
        atomicAdd(&C[(size_t)row * DMODEL + col], acc[tm][tn][r]);
    }
}

// ---------------------------------------------------------------------------
// Gate: softmax((x @ Wg^T).reshape(n, 16, 2), axis=-1) -> float2 per (n,h)
// ---------------------------------------------------------------------------
__global__ __launch_bounds__(256) void gate_kernel(
    const float* __restrict__ x,
    const float* __restrict__ Wg,
    float2* __restrict__ gate)
{
    __shared__ float gs[32];
    const int n = blockIdx.x;
    const int wave = threadIdx.x >> 6, lane = threadIdx.x & 63;
    #pragma unroll
    for (int jj = 0; jj < 8; jj++) {
        int j = wave * 8 + jj;
        float s = 0.f;
        #pragma unroll
        for (int t = 0; t < 16; t++) {
            int d = lane + (t << 6);
            s += x[n * DMODEL + d] * Wg[j * DMODEL + d];
        }
        #pragma unroll
        for (int off = 32; off; off >>= 1) s += __shfl_xor(s, off);
        if (lane == 0) gs[j] = s;
    }
    __syncthreads();
    if (threadIdx.x < NHEAD) {
        int h = threadIdx.x;
        float a = gs[2 * h], b = gs[2 * h + 1];
        float m = fmaxf(a, b);
        float ea = expf(a - m), eb = expf(b - m);
        float inv = 1.f / (ea + eb);
        gate[n * NHEAD + h] = make_float2(ea * inv, eb * inv);
    }
}

// ---------------------------------------------------------------------------
// k_compress[g][f] = mean over c of K[g*64+c][f]
// ---------------------------------------------------------------------------
__global__ __launch_bounds__(256) void kcompress_kernel(
    const float* __restrict__ K, float* __restrict__ kc)
{
    const int g = blockIdx.x;
    for (int f = threadIdx.x; f < DMODEL; f += 256) {
        float s = 0.f;
        #pragma unroll 8
        for (int c = 0; c < CHUNK; c++) s += K[(size_t)(g * CHUNK + c) * DMODEL + f];
        kc[g * DMODEL + f] = s * (1.0f / CHUNK);
    }
}

// ---------------------------------------------------------------------------
// Per-head transpose: Kt[(h*64+d)*1024 + n] = K[n*1024 + h*64 + d]
// ---------------------------------------------------------------------------
__global__ __launch_bounds__(256) void transpose_k_kernel(
    const float* __restrict__ K, float* __restrict__ Kt)
{
    __shared__ float T[64][65];
    const int h = blockIdx.x & 15;
    const int n0 = (blockIdx.x >> 4) * 64;
    for (int i = threadIdx.x; i < 64 * 64; i += 256) {
        int r = i >> 6, d = i & 63;
        T[r][d] = K[(size_t)(n0 + r) * DMODEL + h * HDIM + d];
    }
    __syncthreads();
    for (int i = threadIdx.x; i < 64 * 64; i += 256) {
        int d = i >> 6, nn = i & 63;
        Kt[(size_t)(h * HDIM + d) * NTOK + n0 + nn] = T[nn][d];
    }
}

// ---------------------------------------------------------------------------
// score + top-2 per (n,h), written TRANSPOSED: idx_t[h*1024 + n].
// Mask: g masked if n >= 64*g. Ties -> lowest index (jax.lax.top_k).
// n >= 960: all -inf -> (0,1).
// ---------------------------------------------------------------------------
__global__ __launch_bounds__(256) void score_top2_kernel(
    const float* __restrict__ Q, const float* __restrict__ kc,
    int2* __restrict__ idx_t)
{
    const int t = blockIdx.x * 256 + threadIdx.x;   // t = n*16 + h
    const int n = t >> 4, h = t & 15;
    float q[HDIM];
    #pragma unroll
    for (int d = 0; d < HDIM; d++) q[d] = Q[(size_t)n * DMODEL + h * HDIM + d];
    float sc[NBLK];
    #pragma unroll
    for (int g = 0; g < NBLK; g++) {
        float s = 0.f;
        #pragma unroll
        for (int d = 0; d < HDIM; d++) s += q[d] * kc[g * DMODEL + h * HDIM + d];
        sc[g] = (n >= (g << 6)) ? -INFINITY : s;
    }
    int i1 = -1; float b1 = -INFINITY;
    #pragma unroll
    for (int g = 0; g < NBLK; g++) if (i1 < 0 || sc[g] > b1) { b1 = sc[g]; i1 = g; }
    int i2 = -1; float b2 = -INFINITY;
    #pragma unroll
    for (int g = 0; g < NBLK; g++) { if (g == i1) continue; if (i2 < 0 || sc[g] > b2) { b2 = sc[g]; i2 = g; } }
    idx_t[(h << 10) | n] = make_int2(i1, i2);
}

// ---------------------------------------------------------------------------
// FUSED attention: one wave per (n,h).
//  inter: 2 selected blocks (128 keys), non-causal softmax.
//  intra: own chunk, causal softmax.
//  blend: gate.x * o_inter + gate.y * o_intra, written in-place over Q.
// K accessed via Kt[h][d][n] (coalesced); V rows coalesced. No LDS.
// ---------------------------------------------------------------------------
__global__ __launch_bounds__(256) void attn_fused_kernel(
    float* __restrict__ Q, const float* __restrict__ Kt,
    const float* __restrict__ V, const int2* __restrict__ idx_t,
    const float2* __restrict__ gate)
{
    const int wave = threadIdx.x >> 6, lane = threadIdx.x & 63;
    const int gw = blockIdx.x * 4 + wave;   // = n*16 + h
    const int n = gw >> 4, h = gw & 15;
    const int qi = n & 63;                  // causal position within own chunk
    const int rown = (n >> 6) * CHUNK;      // own chunk base row
    const int2 sel = idx_t[(h << 10) | n];
    const int r1 = sel.x * CHUNK, r2 = sel.y * CHUNK;

    const float qreg = Q[(size_t)n * DMODEL + h * HDIM + lane];
    const float* Kth = Kt + (size_t)h * HDIM * NTOK;

    // scores: lane = key index within each 64-block; 2-way ILP split
    float s0a = 0.f, s0b = 0.f, s1a = 0.f, s1b = 0.f, sia = 0.f, sib = 0.f;
    #pragma unroll 8
    for (int d = 0; d < HDIM; d += 2) {
        float qd0 = __shfl(qreg, d);
        float qd1 = __shfl(qreg, d + 1);
        const float* row0 = Kth + (size_t)d * NTOK;
        const float* row1 = row0 + NTOK;
        s0a += qd0 * row0[r1 + lane];
        s1a += qd0 * row0[r2 + lane];
        sia += qd0 * row0[rown + lane];
        s0b += qd1 * row1[r1 + lane];
        s1b += qd1 * row1[r2 + lane];
        sib += qd1 * row1[rown + lane];
    }
    const float s0 = (s0a + s0b) * 0.125f;
    const float s1 = (s1a + s1b) * 0.125f;
    const float si = (sia + sib) * 0.125f;

    // inter softmax over 128 keys (unnormalized; divide at end)
    float m = fmaxf(s0, s1);
    #pragma unroll
    for (int off = 32; off; off >>= 1) m = fmaxf(m, __shfl_xor(m, off));
    const float e0 = expf(s0 - m), e1 = expf(s1 - m);
    float sum = e0 + e1;
    #pragma unroll
    for (int off = 32; off; off >>= 1) sum += __shfl_xor(sum, off);

    // intra softmax (causal: keys lane > qi masked)
    float sim = (lane > qi) ? -INFINITY : si;
    float mi = sim;
    #pragma unroll
    for (int off = 32; off; off >>= 1) mi = fmaxf(mi, __shfl_xor(mi, off));
    const float ei = (lane > qi) ? 0.f : expf(si - mi);
    float sumi = ei;
    #pragma unroll
    for (int off = 32; off; off >>= 1) sumi += __shfl_xor(sumi, off);

    // PV: lane = dim
    const float* Vh = V + h * HDIM + lane;
    float oa = 0.f, ob = 0.f, oi = 0.f;
    #pragma unroll 4
    for (int k = 0; k < CHUNK; k++) {
        oa += __shfl(e0, k) * Vh[(size_t)(r1 + k) * DMODEL];
        ob += __shfl(e1, k) * Vh[(size_t)(r2 + k) * DMODEL];
    }
    #pragma unroll 4
    for (int k = 0; k <= qi; k++) {        // qi wave-uniform: no divergence
        oi += __shfl(ei, k) * Vh[(size_t)(rown + k) * DMODEL];
    }

    const float2 gt = gate[gw];
    const float val = gt.x * ((oa + ob) / sum) + gt.y * (oi / sumi);
    Q[(size_t)n * DMODEL + h * HDIM + lane] = val;
}

// ---------------------------------------------------------------------------
extern "C" void kernel_launch(void* const* d_in, const int* in_sizes, int n_in,
                              void* d_out, int out_size, void* d_ws, size_t ws_size,
                              hipStream_t stream)
{
    const float* x  = (const float*)d_in[0];
    const float* Wq = (const float*)d_in[1];
    const float* Wk = (const float*)d_in[2];
    const float* Wv = (const float*)d_in[3];
    const float* Wg = (const float*)d_in[4];
    const float* Wo = (const float*)d_in[5];

    // workspace layout (~16.3 MB)
    float* Q       = (float*)d_ws;                    // 4 MB (becomes blended o)
    float* K       = Q + (1 << 20);                   // 4 MB
    float* V       = K + (1 << 20);                   // 4 MB
    float* Kt      = V + (1 << 20);                   // 4 MB (per-head transpose)
    float* kc      = Kt + (1 << 20);                  // 64 KB
    float2* gate   = (float2*)(kc + NBLK * DMODEL);   // 128 KB
    int2* idx_t    = (int2*)(gate + NTOK * NHEAD);    // 128 KB

    dim3 gqkv(48, 16);
    gemm_qkv<<<gqkv, 256, 0, stream>>>(x, Wq, Wk, Wv, Q, K, V);
    gate_kernel<<<NTOK, 256, 0, stream>>>(x, Wg, gate);
    kcompress_kernel<<<NBLK, 256, 0, stream>>>(K, kc);
    transpose_k_kernel<<<256, 256, 0, stream>>>(K, Kt);
    score_top2_kernel<<<NTOK * NHEAD / 256, 256, 0, stream>>>(Q, kc, idx_t);
    // fused inter+intra+blend; writes o in-place over Q
    attn_fused_kernel<<<NTOK * NHEAD / 4, 256, 0, stream>>>(Q, Kt, V, idx_t, gate);

    hipMemsetAsync(d_out, 0, (size_t)NTOK * DMODEL * sizeof(float), stream);
    dim3 gwo(16, 16, 2);
    gemm_wo_splitk<<<gwo, 256, 0, stream>>>(Q, Wo, (float*)d_out);
}